// Round 4
// baseline (903.101 us; speedup 1.0000x reference)
//
#include <hip/hip_runtime.h>
#include <stdint.h>

#define T_TOK 2048
#define D_IN  2048
#define H_I   1024
#define NE    16
#define TOPK  4
#define TWOH  2048
#define MAX_SLOTS 12288   // 16 experts padded (<=10224) + 2048 shared
#define MAX_TILES 96      // MAX_SLOTS / 128

typedef __attribute__((ext_vector_type(8))) __bf16 bf16x8;
typedef __attribute__((ext_vector_type(4))) float  f32x4;

__device__ __forceinline__ unsigned short f2bf(float f) {
  unsigned u = __float_as_uint(f);
  u += 0x7FFF + ((u >> 16) & 1);          // round-to-nearest-even
  return (unsigned short)(u >> 16);
}
__device__ __forceinline__ float bf2f(unsigned short s) {
  return __uint_as_float(((unsigned)s) << 16);
}

// per-block group metadata from cnt[] (compact_lists / reduce_out only)
__device__ __forceinline__ void group_meta(const int* __restrict__ cnt, int g,
                                           int& base, int& pc, int& shared_base) {
  int o = 0; base = 0; pc = T_TOK;
  for (int e = 0; e < NE; ++e) {
    int pce = (cnt[e] + 127) & ~127;
    if (e == g) { base = o; pc = pce; }
    o += pce;
  }
  shared_base = o;
  if (g == 16) base = o;
}

// async 16B global->LDS (lds dest = wave-uniform base + lane*16)
#define GLDS16(gp, lp) __builtin_amdgcn_global_load_lds( \
    (__attribute__((address_space(1))) void*)(gp),       \
    (__attribute__((address_space(3))) void*)(lp), 16, 0, 0)

// ---------------- fp32 -> bf16 convert, all tensors in one kernel ----------------
// float4 ranges: x 1048576 | w1 16777216 | w2 8388608 | sw1 1048576 | sw2 524288
#define R_X   1048576
#define R_W1  (R_X + 16777216)     // 17825792
#define R_W2  (R_W1 + 8388608)     // 26214400
#define R_SW1 (R_W2 + 1048576)     // 27262976
#define R_SW2 (R_SW1 + 524288)     // 27787264
__global__ void cvt_all(const float4* __restrict__ x,  const float4* __restrict__ w1,
                        const float4* __restrict__ w2, const float4* __restrict__ sw1,
                        const float4* __restrict__ sw2,
                        ushort4* __restrict__ xd,  ushort4* __restrict__ w1d,
                        ushort4* __restrict__ w2d, ushort4* __restrict__ sw1d,
                        ushort4* __restrict__ sw2d, int* __restrict__ cnt) {
  int i = blockIdx.x * 256 + threadIdx.x;
  if (i < NE) cnt[i] = 0;          // zero expert counters (stream-ordered before gate_topk)
  const float4* s; ushort4* d; int j;
  if      (i < R_X)   { s = x;   d = xd;   j = i; }
  else if (i < R_W1)  { s = w1;  d = w1d;  j = i - R_X; }
  else if (i < R_W2)  { s = w2;  d = w2d;  j = i - R_W1; }
  else if (i < R_SW1) { s = sw1; d = sw1d; j = i - R_W2; }
  else if (i < R_SW2) { s = sw2; d = sw2d; j = i - R_SW1; }
  else return;
  float4 f = s[j];
  ushort4 u;
  u.x = f2bf(f.x); u.y = f2bf(f.y); u.z = f2bf(f.z); u.w = f2bf(f.w);
  d[j] = u;
}

// ---------------- gate: logits -> softmax -> top4 -> per-expert lists ----------------
__global__ __launch_bounds__(256) void gate_topk(
    const float* __restrict__ x, const float* __restrict__ gw,
    int* __restrict__ cnt, int* __restrict__ cap_tok, float* __restrict__ cap_w,
    int* __restrict__ tk_ep)
{
  int t = blockIdx.x;
  const float* xr = x + (size_t)t * D_IN;
  float acc[NE];
#pragma unroll
  for (int e = 0; e < NE; ++e) acc[e] = 0.f;
  for (int d = threadIdx.x; d < D_IN; d += 256) {
    float xv = xr[d];
#pragma unroll
    for (int e = 0; e < NE; ++e) acc[e] += xv * gw[e * D_IN + d];
  }
#pragma unroll
  for (int e = 0; e < NE; ++e) {
    float v = acc[e];
#pragma unroll
    for (int o = 32; o > 0; o >>= 1) v += __shfl_down(v, o, 64);
    acc[e] = v;
  }
  __shared__ float red[4][NE];
  int wv = threadIdx.x >> 6, ln = threadIdx.x & 63;
  if (ln == 0) {
#pragma unroll
    for (int e = 0; e < NE; ++e) red[wv][e] = acc[e];
  }
  __syncthreads();
  if (threadIdx.x == 0) {
    float lg[NE];
    float mx = -1e30f;
#pragma unroll
    for (int e = 0; e < NE; ++e) {
      lg[e] = red[0][e] + red[1][e] + red[2][e] + red[3][e];
      mx = fmaxf(mx, lg[e]);
    }
    float s = 0.f;
#pragma unroll
    for (int e = 0; e < NE; ++e) { lg[e] = __expf(lg[e] - mx); s += lg[e]; }
    float inv = 1.f / s;
    bool used[NE] = {};
    for (int k = 0; k < TOPK; ++k) {
      float best = -1.f; int bi = 0;
      for (int e = 0; e < NE; ++e)
        if (!used[e] && lg[e] > best) { best = lg[e]; bi = e; }
      used[bi] = true;
      int pos = atomicAdd(&cnt[bi], 1);
      cap_tok[bi * T_TOK + pos] = t;
      cap_w[bi * T_TOK + pos]   = best * inv;
      tk_ep[t * TOPK + k] = (bi << 16) | pos;   // compaction preserves pos
    }
  }
}

// threads: [0, NE*T) expert caps | [NE*T, NE*T+T) shared | [.., +4T) tok2slot
// idx==0 additionally builds the dense worker-tile map: tmap[k] = (g<<16)|base_slot,
// tmap[MAX_TILES] = ntiles. This kills the CU load-imbalance of the g*256+rem layout.
__global__ void compact_lists(const int* __restrict__ cnt,
                              const int* __restrict__ cap_tok, const float* __restrict__ cap_w,
                              const int* __restrict__ tk_ep,
                              int* __restrict__ stok, float* __restrict__ swt,
                              int* __restrict__ tok2slot, int* __restrict__ tmap)
{
  int idx = blockIdx.x * 256 + threadIdx.x;
  if (idx == 0) {
    int k = 0, o = 0;
    for (int e = 0; e < NE; ++e) {
      int pce = (cnt[e] + 127) & ~127;
      for (int m = 0; m * 128 < pce && k < MAX_TILES; ++m)
        tmap[k++] = (e << 16) | (o + m * 128);
      o += pce;
    }
    for (int m = 0; m < 16 && k < MAX_TILES; ++m)
      tmap[k++] = (16 << 16) | (o + m * 128);
    tmap[MAX_TILES] = k;
  }
  if (idx < NE * T_TOK) {
    int e = idx >> 11, pos = idx & (T_TOK - 1);
    int base, pc, sb;
    group_meta(cnt, e, base, pc, sb);
    if (pos < pc) {
      int dst = base + pos;
      if (pos < cnt[e]) { stok[dst] = cap_tok[idx]; swt[dst] = cap_w[idx]; }
      else              { stok[dst] = 0;            swt[dst] = 0.f; }
    }
  } else if (idx < NE * T_TOK + T_TOK) {
    int t = idx - NE * T_TOK;
    int base, pc, sb;
    group_meta(cnt, 16, base, pc, sb);
    stok[base + t] = t; swt[base + t] = 1.f;
  } else {
    int j = idx - NE * T_TOK - T_TOK;          // j in [0, 4T)
    int ep = tk_ep[j];
    int e = ep >> 16;
    int base, pc, sb;
    group_meta(cnt, e, base, pc, sb);
    tok2slot[j] = base + (ep & 0xFFFF);
  }
}

// ---------------- fused fc1 + silu-gating (BK=64) ----------------
// Block tile: 128 slots x 64 h-cols. B-rows staged: [0,64)=y rows nt*64+j,
// [64,128)=gate rows 1024+nt*64+j. wn=0 waves hold y-acc, wn=1 gate-acc.
// Epilogue: wn=1 -> silu(g) via LDS (XOR-swizzled), wn=0 -> h=y*s*wt bf16.
// Dense tile decode: tile = bx>>4 via tmap (contiguous workers -> even CU load);
// same (g,nt) panel-sharers remain at bx-stride 16 == 0 mod 8 -> same-XCD B reuse.
__global__ __launch_bounds__(256) void fc1_fused(
    const unsigned short* __restrict__ xbf,
    const unsigned short* __restrict__ w1bf,
    const unsigned short* __restrict__ sw1bf,
    const int* __restrict__ stok, const float* __restrict__ swt,
    const int* __restrict__ tmap,
    unsigned short* __restrict__ hbuf)
{
  int bx = blockIdx.x;
  int tile = bx >> 4, nt = bx & 15;
  if (tile >= tmap[MAX_TILES]) return;
  int tg = tmap[tile];
  int g = tg >> 16, base_slot = tg & 0xFFFF;
  const unsigned short* B = (g == 16) ? sw1bf : w1bf + (size_t)g * TWOH * D_IN;

  __shared__ __align__(16) unsigned char smem[32768];
  auto sA = (unsigned short (*)[128][8])smem;            // [8][128][8] 16 KB
  auto sB = (unsigned short (*)[128][8])(smem + 16384);  // [8][128][8] 16 KB
  auto sG = (float (*)[64])smem;                         // [128][64] 32 KB (epilogue alias)

  int tid = threadIdx.x;
  int w = tid >> 6, l = tid & 63;
  int lm = l & 15, q = l >> 4;
  int wm = w >> 1, wn = w & 1;

  const unsigned short* a0 = xbf + (size_t)stok[base_slot + l]      * D_IN + w * 16;
  const unsigned short* a1 = xbf + (size_t)stok[base_slot + 64 + l] * D_IN + w * 16;
  const unsigned short* b0 = B + (size_t)(nt * 64 + l)       * D_IN + w * 16;  // y rows
  const unsigned short* b1 = B + (size_t)(H_I + nt * 64 + l) * D_IN + w * 16;  // gate rows

  f32x4 acc[4][4];
#pragma unroll
  for (int i = 0; i < 4; ++i)
#pragma unroll
    for (int j = 0; j < 4; ++j) acc[i][j] = (f32x4){0.f, 0.f, 0.f, 0.f};

  for (int kt = 0; kt < D_IN; kt += 64) {
    GLDS16(a0 + kt,     &sA[2 * w][0][0]);
    GLDS16(a0 + kt + 8, &sA[2 * w + 1][0][0]);
    GLDS16(a1 + kt,     &sA[2 * w][64][0]);
    GLDS16(a1 + kt + 8, &sA[2 * w + 1][64][0]);
    GLDS16(b0 + kt,     &sB[2 * w][0][0]);
    GLDS16(b0 + kt + 8, &sB[2 * w + 1][0][0]);
    GLDS16(b1 + kt,     &sB[2 * w][64][0]);
    GLDS16(b1 + kt + 8, &sB[2 * w + 1][64][0]);
    __syncthreads();
    bf16x8 af[2][4], bfr[2][4];
#pragma unroll
    for (int s = 0; s < 2; ++s) {
#pragma unroll
      for (int i = 0; i < 4; ++i) af[s][i]  = *(const bf16x8*)&sA[4 * s + q][wm * 64 + i * 16 + lm][0];
#pragma unroll
      for (int j = 0; j < 4; ++j) bfr[s][j] = *(const bf16x8*)&sB[4 * s + q][wn * 64 + j * 16 + lm][0];
    }
#pragma unroll
    for (int s = 0; s < 2; ++s)
#pragma unroll
      for (int i = 0; i < 4; ++i)
#pragma unroll
        for (int j = 0; j < 4; ++j)
          acc[i][j] = __builtin_amdgcn_mfma_f32_16x16x32_bf16(af[s][i], bfr[s][j], acc[i][j], 0, 0, 0);
    __syncthreads();
  }

  // epilogue: gate waves push silu(g) through LDS (alias over sA/sB — safe after barrier)
  if (wn == 1) {
#pragma unroll
    for (int i = 0; i < 4; ++i)
#pragma unroll
      for (int r = 0; r < 4; ++r) {
        int row = wm * 64 + i * 16 + q * 4 + r;
        int sw = (row & 3) << 4;                 // XOR swizzle: <=2-way bank alias (free)
#pragma unroll
        for (int j = 0; j < 4; ++j) {
          float gv = acc[i][j][r];
          sG[row][(j * 16 + lm) ^ sw] = gv / (1.f + __expf(-gv));
        }
      }
  }
  __syncthreads();
  if (wn == 0) {
#pragma unroll
    for (int i = 0; i < 4; ++i)
#pragma unroll
      for (int r = 0; r < 4; ++r) {
        int row = wm * 64 + i * 16 + q * 4 + r;
        int slot = base_slot + row;
        float wt = swt[slot];
        int sw = (row & 3) << 4;
        unsigned short* hrow = hbuf + (size_t)slot * H_I + nt * 64;
#pragma unroll
        for (int j = 0; j < 4; ++j) {
          int col = j * 16 + lm;
          hrow[col] = f2bf(acc[i][j][r] * sG[row][col ^ sw] * wt);
        }
      }
  }
}

// ---------------- grouped GEMM fc2 (BK=64): Yout[slot, 0:2048] = h[slot] @ W2_g^T, bf16 out ----------------
__global__ __launch_bounds__(256) void fc2_gemm(
    const unsigned short* __restrict__ hbuf,
    const unsigned short* __restrict__ w2bf,
    const unsigned short* __restrict__ sw2bf,
    const int* __restrict__ tmap,
    unsigned short* __restrict__ Yout)
{
  int bx = blockIdx.x;
  int tile = bx >> 4, nt = bx & 15;
  if (tile >= tmap[MAX_TILES]) return;
  int tg = tmap[tile];
  int g = tg >> 16, base_slot = tg & 0xFFFF;
  const unsigned short* B = (g == 16) ? sw2bf : w2bf + (size_t)g * D_IN * H_I;

  __shared__ __align__(16) unsigned short sA[8][128][8];
  __shared__ __align__(16) unsigned short sB[8][128][8];

  int tid = threadIdx.x;
  int w = tid >> 6, l = tid & 63;
  int lm = l & 15, q = l >> 4;
  int wm = w >> 1, wn = w & 1;

  const unsigned short* a0 = hbuf + (size_t)(base_slot + l)      * H_I + w * 16;
  const unsigned short* a1 = hbuf + (size_t)(base_slot + 64 + l) * H_I + w * 16;
  const unsigned short* b0 = B + (size_t)(nt * 128 + l)      * H_I + w * 16;
  const unsigned short* b1 = B + (size_t)(nt * 128 + 64 + l) * H_I + w * 16;

  f32x4 acc[4][4];
#pragma unroll
  for (int i = 0; i < 4; ++i)
#pragma unroll
    for (int j = 0; j < 4; ++j) acc[i][j] = (f32x4){0.f, 0.f, 0.f, 0.f};

  for (int kt = 0; kt < H_I; kt += 64) {
    GLDS16(a0 + kt,     &sA[2 * w][0][0]);
    GLDS16(a0 + kt + 8, &sA[2 * w + 1][0][0]);
    GLDS16(a1 + kt,     &sA[2 * w][64][0]);
    GLDS16(a1 + kt + 8, &sA[2 * w + 1][64][0]);
    GLDS16(b0 + kt,     &sB[2 * w][0][0]);
    GLDS16(b0 + kt + 8, &sB[2 * w + 1][0][0]);
    GLDS16(b1 + kt,     &sB[2 * w][64][0]);
    GLDS16(b1 + kt + 8, &sB[2 * w + 1][64][0]);
    __syncthreads();
    bf16x8 af[2][4], bfr[2][4];
#pragma unroll
    for (int s = 0; s < 2; ++s) {
#pragma unroll
      for (int i = 0; i < 4; ++i) af[s][i]  = *(const bf16x8*)&sA[4 * s + q][wm * 64 + i * 16 + lm][0];
#pragma unroll
      for (int j = 0; j < 4; ++j) bfr[s][j] = *(const bf16x8*)&sB[4 * s + q][wn * 64 + j * 16 + lm][0];
    }
#pragma unroll
    for (int s = 0; s < 2; ++s)
#pragma unroll
      for (int i = 0; i < 4; ++i)
#pragma unroll
        for (int j = 0; j < 4; ++j)
          acc[i][j] = __builtin_amdgcn_mfma_f32_16x16x32_bf16(af[s][i], bfr[s][j], acc[i][j], 0, 0, 0);
    __syncthreads();
  }

  int colbase = nt * 128 + wn * 64;
#pragma unroll
  for (int i = 0; i < 4; ++i) {
#pragma unroll
    for (int r = 0; r < 4; ++r) {
      int row = wm * 64 + i * 16 + q * 4 + r;
      unsigned short* orow = Yout + (size_t)(base_slot + row) * D_IN + colbase + lm;
#pragma unroll
      for (int j = 0; j < 4; ++j)
        orow[j * 16] = f2bf(acc[i][j][r]);
    }
  }
}

// ---------------- out[t] = sum_k Yout[slot_k(t)] + Yout[shared_slot(t)] ----------------
__global__ __launch_bounds__(256) void reduce_out(
    const unsigned short* __restrict__ Yout, const int* __restrict__ tok2slot,
    const int* __restrict__ cnt, float4* __restrict__ out)
{
  int idx = blockIdx.x * 256 + threadIdx.x;   // [0, T*512)
  int t = idx >> 9, c = (idx & 511) << 2;     // 4 cols per thread
  int sb = 0;
  for (int e = 0; e < NE; ++e) sb += (cnt[e] + 127) & ~127;
  int sl[5];
  sl[0] = sb + t;
#pragma unroll
  for (int k = 0; k < TOPK; ++k) sl[k + 1] = tok2slot[t * TOPK + k];
  float4 a = {0.f, 0.f, 0.f, 0.f};
#pragma unroll
  for (int k = 0; k < 5; ++k) {
    ushort4 v = *(const ushort4*)(Yout + (size_t)sl[k] * D_IN + c);
    a.x += bf2f(v.x); a.y += bf2f(v.y); a.z += bf2f(v.z); a.w += bf2f(v.w);
  }
  out[idx] = a;
}

extern "C" void kernel_launch(void* const* d_in, const int* in_sizes, int n_in,
                              void* d_out, int out_size, void* d_ws, size_t ws_size,
                              hipStream_t stream)
{
  const float* x   = (const float*)d_in[0];
  const float* gw  = (const float*)d_in[1];
  const float* w1  = (const float*)d_in[2];
  const float* w2  = (const float*)d_in[3];
  const float* sw1 = (const float*)d_in[4];
  const float* sw2 = (const float*)d_in[5];
  float* out = (float*)d_out;

  char* ws = (char*)d_ws;
  size_t off = 0;
  auto alloc = [&](size_t bytes) -> char* {
    char* p = ws + off; off += (bytes + 255) & ~(size_t)255; return p;
  };
  unsigned short* xbf   = (unsigned short*)alloc((size_t)T_TOK * D_IN * 2);
  unsigned short* w1bf  = (unsigned short*)alloc((size_t)NE * TWOH * D_IN * 2);   // 128 MB; reused as Yout
  unsigned short* w2bf  = (unsigned short*)alloc((size_t)NE * D_IN * H_I * 2);
  unsigned short* sw1bf = (unsigned short*)alloc((size_t)TWOH * D_IN * 2);
  unsigned short* sw2bf = (unsigned short*)alloc((size_t)D_IN * H_I * 2);
  unsigned short* hbuf  = (unsigned short*)alloc((size_t)MAX_SLOTS * H_I * 2);
  int*   cnt    = (int*)alloc(NE * 4);
  int*   captok = (int*)alloc((size_t)NE * T_TOK * 4);
  float* capw   = (float*)alloc((size_t)NE * T_TOK * 4);
  int*   stok   = (int*)alloc(MAX_SLOTS * 4);
  float* swt    = (float*)alloc(MAX_SLOTS * 4);
  int*   tk_ep  = (int*)alloc((size_t)T_TOK * TOPK * 4);
  int*   t2s    = (int*)alloc((size_t)T_TOK * TOPK * 4);
  int*   tmap   = (int*)alloc((MAX_TILES + 1) * 4);
  if (off > ws_size) return;  // ws too small: leave out poisoned as diagnostic

  // fc2 output (bf16) aliases w1bf (dead after fc1): 12288*2048*2 = 50.3 MB <= 128 MB
  unsigned short* Yout = (unsigned short*)w1bf;

  cvt_all<<<(R_SW2 + 255) / 256, 256, 0, stream>>>(
      (const float4*)x, (const float4*)w1, (const float4*)w2,
      (const float4*)sw1, (const float4*)sw2,
      (ushort4*)xbf, (ushort4*)w1bf, (ushort4*)w2bf, (ushort4*)sw1bf, (ushort4*)sw2bf, cnt);

  gate_topk<<<T_TOK, 256, 0, stream>>>(x, gw, cnt, captok, capw, tk_ep);
  compact_lists<<<(NE * T_TOK + T_TOK + TOPK * T_TOK) / 256, 256, 0, stream>>>(
      cnt, captok, capw, tk_ep, stok, swt, t2s, tmap);
  fc1_fused<<<MAX_TILES * 16, 256, 0, stream>>>(xbf, w1bf, sw1bf, stok, swt, tmap, hbuf);
  fc2_gemm<<<MAX_TILES * 16, 256, 0, stream>>>(hbuf, w2bf, sw2bf, tmap, Yout);
  reduce_out<<<(T_TOK * 512) / 256, 256, 0, stream>>>(Yout, t2s, cnt, (float4*)out);
}

// Round 5
// 794.446 us; speedup vs baseline: 1.1368x; 1.1368x over previous
//
#include <hip/hip_runtime.h>
#include <stdint.h>

#define T_TOK 2048
#define D_IN  2048
#define H_I   1024
#define NE    16
#define TOPK  4
#define TWOH  2048
#define MAX_SLOTS 12288   // 16 experts padded (<=10224) + 2048 shared
#define MAX_TILES 96      // MAX_SLOTS / 128

typedef __attribute__((ext_vector_type(8))) __bf16 bf16x8;
typedef __attribute__((ext_vector_type(4))) float  f32x4;

__device__ __forceinline__ unsigned short f2bf(float f) {
  unsigned u = __float_as_uint(f);
  u += 0x7FFF + ((u >> 16) & 1);          // round-to-nearest-even
  return (unsigned short)(u >> 16);
}
__device__ __forceinline__ float bf2f(unsigned short s) {
  return __uint_as_float(((unsigned)s) << 16);
}

// per-block group metadata from cnt[] (compact_lists / reduce_out only)
__device__ __forceinline__ void group_meta(const int* __restrict__ cnt, int g,
                                           int& base, int& pc, int& shared_base) {
  int o = 0; base = 0; pc = T_TOK;
  for (int e = 0; e < NE; ++e) {
    int pce = (cnt[e] + 127) & ~127;
    if (e == g) { base = o; pc = pce; }
    o += pce;
  }
  shared_base = o;
  if (g == 16) base = o;
}

// async 16B global->LDS (lds dest = wave-uniform base + lane*16)
#define GLDS16(gp, lp) __builtin_amdgcn_global_load_lds( \
    (__attribute__((address_space(1))) void*)(gp),       \
    (__attribute__((address_space(3))) void*)(lp), 16, 0, 0)

// ---------------- fp32 -> bf16 convert, all tensors in one kernel ----------------
// float4 ranges: x 1048576 | w1 16777216 | w2 8388608 | sw1 1048576 | sw2 524288
#define R_X   1048576
#define R_W1  (R_X + 16777216)     // 17825792
#define R_W2  (R_W1 + 8388608)     // 26214400
#define R_SW1 (R_W2 + 1048576)     // 27262976
#define R_SW2 (R_SW1 + 524288)     // 27787264
__global__ void cvt_all(const float4* __restrict__ x,  const float4* __restrict__ w1,
                        const float4* __restrict__ w2, const float4* __restrict__ sw1,
                        const float4* __restrict__ sw2,
                        ushort4* __restrict__ xd,  ushort4* __restrict__ w1d,
                        ushort4* __restrict__ w2d, ushort4* __restrict__ sw1d,
                        ushort4* __restrict__ sw2d, int* __restrict__ cnt) {
  int i = blockIdx.x * 256 + threadIdx.x;
  if (i < NE) cnt[i] = 0;          // zero expert counters (stream-ordered before gate_topk)
  const float4* s; ushort4* d; int j;
  if      (i < R_X)   { s = x;   d = xd;   j = i; }
  else if (i < R_W1)  { s = w1;  d = w1d;  j = i - R_X; }
  else if (i < R_W2)  { s = w2;  d = w2d;  j = i - R_W1; }
  else if (i < R_SW1) { s = sw1; d = sw1d; j = i - R_W2; }
  else if (i < R_SW2) { s = sw2; d = sw2d; j = i - R_SW1; }
  else return;
  float4 f = s[j];
  ushort4 u;
  u.x = f2bf(f.x); u.y = f2bf(f.y); u.z = f2bf(f.z); u.w = f2bf(f.w);
  d[j] = u;
}

// ---------------- gate: logits -> softmax -> top4 -> per-expert lists ----------------
__global__ __launch_bounds__(256) void gate_topk(
    const float* __restrict__ x, const float* __restrict__ gw,
    int* __restrict__ cnt, int* __restrict__ cap_tok, float* __restrict__ cap_w,
    int* __restrict__ tk_ep)
{
  int t = blockIdx.x;
  const float* xr = x + (size_t)t * D_IN;
  float acc[NE];
#pragma unroll
  for (int e = 0; e < NE; ++e) acc[e] = 0.f;
  for (int d = threadIdx.x; d < D_IN; d += 256) {
    float xv = xr[d];
#pragma unroll
    for (int e = 0; e < NE; ++e) acc[e] += xv * gw[e * D_IN + d];
  }
#pragma unroll
  for (int e = 0; e < NE; ++e) {
    float v = acc[e];
#pragma unroll
    for (int o = 32; o > 0; o >>= 1) v += __shfl_down(v, o, 64);
    acc[e] = v;
  }
  __shared__ float red[4][NE];
  int wv = threadIdx.x >> 6, ln = threadIdx.x & 63;
  if (ln == 0) {
#pragma unroll
    for (int e = 0; e < NE; ++e) red[wv][e] = acc[e];
  }
  __syncthreads();
  if (threadIdx.x == 0) {
    float lg[NE];
    float mx = -1e30f;
#pragma unroll
    for (int e = 0; e < NE; ++e) {
      lg[e] = red[0][e] + red[1][e] + red[2][e] + red[3][e];
      mx = fmaxf(mx, lg[e]);
    }
    float s = 0.f;
#pragma unroll
    for (int e = 0; e < NE; ++e) { lg[e] = __expf(lg[e] - mx); s += lg[e]; }
    float inv = 1.f / s;
    bool used[NE] = {};
    for (int k = 0; k < TOPK; ++k) {
      float best = -1.f; int bi = 0;
      for (int e = 0; e < NE; ++e)
        if (!used[e] && lg[e] > best) { best = lg[e]; bi = e; }
      used[bi] = true;
      int pos = atomicAdd(&cnt[bi], 1);
      cap_tok[bi * T_TOK + pos] = t;
      cap_w[bi * T_TOK + pos]   = best * inv;
      tk_ep[t * TOPK + k] = (bi << 16) | pos;   // compaction preserves pos
    }
  }
}

// threads: [0, NE*T) expert caps | [NE*T, NE*T+T) shared | [.., +4T) tok2slot
// idx==0 additionally builds the dense worker-tile map: tmap[k] = (g<<16)|base_slot,
// tmap[MAX_TILES] = ntiles.
__global__ void compact_lists(const int* __restrict__ cnt,
                              const int* __restrict__ cap_tok, const float* __restrict__ cap_w,
                              const int* __restrict__ tk_ep,
                              int* __restrict__ stok, float* __restrict__ swt,
                              int* __restrict__ tok2slot, int* __restrict__ tmap)
{
  int idx = blockIdx.x * 256 + threadIdx.x;
  if (idx == 0) {
    int k = 0, o = 0;
    for (int e = 0; e < NE; ++e) {
      int pce = (cnt[e] + 127) & ~127;
      for (int m = 0; m * 128 < pce && k < MAX_TILES; ++m)
        tmap[k++] = (e << 16) | (o + m * 128);
      o += pce;
    }
    for (int m = 0; m < 16 && k < MAX_TILES; ++m)
      tmap[k++] = (16 << 16) | (o + m * 128);
    tmap[MAX_TILES] = k;
  }
  if (idx < NE * T_TOK) {
    int e = idx >> 11, pos = idx & (T_TOK - 1);
    int base, pc, sb;
    group_meta(cnt, e, base, pc, sb);
    if (pos < pc) {
      int dst = base + pos;
      if (pos < cnt[e]) { stok[dst] = cap_tok[idx]; swt[dst] = cap_w[idx]; }
      else              { stok[dst] = 0;            swt[dst] = 0.f; }
    }
  } else if (idx < NE * T_TOK + T_TOK) {
    int t = idx - NE * T_TOK;
    int base, pc, sb;
    group_meta(cnt, 16, base, pc, sb);
    stok[base + t] = t; swt[base + t] = 1.f;
  } else {
    int j = idx - NE * T_TOK - T_TOK;          // j in [0, 4T)
    int ep = tk_ep[j];
    int e = ep >> 16;
    int base, pc, sb;
    group_meta(cnt, e, base, pc, sb);
    tok2slot[j] = base + (ep & 0xFFFF);
  }
}

// ---------------- fused fc1 + silu-gating (BK=64, coalesced 8-row staging) ----------------
// LDS per K-step: sA[128][64], sB[128][64] bf16 (16KB each).
// Staging: lane (r=l>>3, c=l&7); each GLDS16 covers 8 rows x full 128B K-slice
// (1 cache line per row -> 8 lines/instr vs 64 for the old 64-row gather).
// Global source is pre-swizzled by chunk c^r; ds_read applies chunk ^ (lm&7)
// (G4 XOR fix for the 128B-stride bank trap; involution verified).
__global__ __launch_bounds__(256) void fc1_fused(
    const unsigned short* __restrict__ xbf,
    const unsigned short* __restrict__ w1bf,
    const unsigned short* __restrict__ sw1bf,
    const int* __restrict__ stok, const float* __restrict__ swt,
    const int* __restrict__ tmap,
    unsigned short* __restrict__ hbuf)
{
  int bx = blockIdx.x;
  int tile = bx >> 4, nt = bx & 15;
  if (tile >= tmap[MAX_TILES]) return;
  int tg = tmap[tile];
  int g = tg >> 16, base_slot = tg & 0xFFFF;
  const unsigned short* B = (g == 16) ? sw1bf : w1bf + (size_t)g * TWOH * D_IN;

  __shared__ __align__(16) unsigned char smem[32768];
  auto sA = (unsigned short (*)[64])smem;             // [128][64] 16 KB
  auto sB = (unsigned short (*)[64])(smem + 16384);   // [128][64] 16 KB
  auto sG = (float (*)[64])smem;                      // [128][64] 32 KB (epilogue alias)

  int tid = threadIdx.x;
  int w = tid >> 6, l = tid & 63;
  int lm = l & 15, q = l >> 4;
  int wm = w >> 1, wn = w & 1;
  int r = l >> 3, c = l & 7;
  int csw = (c ^ r) << 3;          // pre-swizzled element offset within the 64-wide K-step

  // A: 16 chunks of 8 rows; wave w owns chunks 4w..4w+3 (rows w*32 .. w*32+31)
  const unsigned short* pA0 = xbf + (size_t)stok[base_slot + w * 32 +  0 + r] * D_IN + csw;
  const unsigned short* pA1 = xbf + (size_t)stok[base_slot + w * 32 +  8 + r] * D_IN + csw;
  const unsigned short* pA2 = xbf + (size_t)stok[base_slot + w * 32 + 16 + r] * D_IN + csw;
  const unsigned short* pA3 = xbf + (size_t)stok[base_slot + w * 32 + 24 + r] * D_IN + csw;
  // B: chunks cb = 4w..4w+3 of 16; cb<8 -> y row nt*64+8cb+r, cb>=8 -> gate row H_I+nt*64+8(cb-8)+r
  int cb0 = w * 4;
  int br0 = (cb0 + 0 < 8) ? (nt * 64 + (cb0 + 0) * 8 + r) : (H_I + nt * 64 + (cb0 - 8) * 8 + r);
  int br1 = (cb0 + 1 < 8) ? (nt * 64 + (cb0 + 1) * 8 + r) : (H_I + nt * 64 + (cb0 - 7) * 8 + r);
  int br2 = (cb0 + 2 < 8) ? (nt * 64 + (cb0 + 2) * 8 + r) : (H_I + nt * 64 + (cb0 - 6) * 8 + r);
  int br3 = (cb0 + 3 < 8) ? (nt * 64 + (cb0 + 3) * 8 + r) : (H_I + nt * 64 + (cb0 - 5) * 8 + r);
  const unsigned short* pB0 = B + (size_t)br0 * D_IN + csw;
  const unsigned short* pB1 = B + (size_t)br1 * D_IN + csw;
  const unsigned short* pB2 = B + (size_t)br2 * D_IN + csw;
  const unsigned short* pB3 = B + (size_t)br3 * D_IN + csw;

  f32x4 acc[4][4];
#pragma unroll
  for (int i = 0; i < 4; ++i)
#pragma unroll
    for (int j = 0; j < 4; ++j) acc[i][j] = (f32x4){0.f, 0.f, 0.f, 0.f};

  for (int kt = 0; kt < D_IN; kt += 64) {
    GLDS16(pA0 + kt, &sA[w * 32 +  0][0]);
    GLDS16(pA1 + kt, &sA[w * 32 +  8][0]);
    GLDS16(pA2 + kt, &sA[w * 32 + 16][0]);
    GLDS16(pA3 + kt, &sA[w * 32 + 24][0]);
    GLDS16(pB0 + kt, &sB[w * 32 +  0][0]);
    GLDS16(pB1 + kt, &sB[w * 32 +  8][0]);
    GLDS16(pB2 + kt, &sB[w * 32 + 16][0]);
    GLDS16(pB3 + kt, &sB[w * 32 + 24][0]);
    __syncthreads();
    bf16x8 af[2][4], bfr[2][4];
#pragma unroll
    for (int s = 0; s < 2; ++s) {
#pragma unroll
      for (int i = 0; i < 4; ++i) {
        int row = wm * 64 + i * 16 + lm;
        af[s][i] = *(const bf16x8*)&sA[row][(((s << 2) + q) ^ (lm & 7)) << 3];
      }
#pragma unroll
      for (int j = 0; j < 4; ++j) {
        int row = wn * 64 + j * 16 + lm;
        bfr[s][j] = *(const bf16x8*)&sB[row][(((s << 2) + q) ^ (lm & 7)) << 3];
      }
    }
#pragma unroll
    for (int s = 0; s < 2; ++s)
#pragma unroll
      for (int i = 0; i < 4; ++i)
#pragma unroll
        for (int j = 0; j < 4; ++j)
          acc[i][j] = __builtin_amdgcn_mfma_f32_16x16x32_bf16(af[s][i], bfr[s][j], acc[i][j], 0, 0, 0);
    __syncthreads();
  }

  // epilogue: gate waves push silu(g) through LDS (alias over sA/sB — safe after barrier)
  if (wn == 1) {
#pragma unroll
    for (int i = 0; i < 4; ++i)
#pragma unroll
      for (int rr = 0; rr < 4; ++rr) {
        int row = wm * 64 + i * 16 + q * 4 + rr;
        int sw = (row & 3) << 4;                 // XOR swizzle: <=2-way bank alias (free)
#pragma unroll
        for (int j = 0; j < 4; ++j) {
          float gv = acc[i][j][rr];
          sG[row][(j * 16 + lm) ^ sw] = gv / (1.f + __expf(-gv));
        }
      }
  }
  __syncthreads();
  if (wn == 0) {
#pragma unroll
    for (int i = 0; i < 4; ++i)
#pragma unroll
      for (int rr = 0; rr < 4; ++rr) {
        int row = wm * 64 + i * 16 + q * 4 + rr;
        int slot = base_slot + row;
        float wt = swt[slot];
        int sw = (row & 3) << 4;
        unsigned short* hrow = hbuf + (size_t)slot * H_I + nt * 64;
#pragma unroll
        for (int j = 0; j < 4; ++j) {
          int col = j * 16 + lm;
          hrow[col] = f2bf(acc[i][j][rr] * sG[row][col ^ sw] * wt);
        }
      }
  }
}

// ---------------- grouped GEMM fc2 (BK=64, coalesced 8-row staging) ----------------
// Yout[slot, 0:2048] = h[slot] @ W2_g^T, bf16 out. Same staging/swizzle scheme as fc1.
__global__ __launch_bounds__(256) void fc2_gemm(
    const unsigned short* __restrict__ hbuf,
    const unsigned short* __restrict__ w2bf,
    const unsigned short* __restrict__ sw2bf,
    const int* __restrict__ tmap,
    unsigned short* __restrict__ Yout)
{
  int bx = blockIdx.x;
  int tile = bx >> 4, nt = bx & 15;
  if (tile >= tmap[MAX_TILES]) return;
  int tg = tmap[tile];
  int g = tg >> 16, base_slot = tg & 0xFFFF;
  const unsigned short* B = (g == 16) ? sw2bf : w2bf + (size_t)g * D_IN * H_I;

  __shared__ __align__(16) unsigned char smem[32768];
  auto sA = (unsigned short (*)[64])smem;             // [128][64]
  auto sB = (unsigned short (*)[64])(smem + 16384);   // [128][64]

  int tid = threadIdx.x;
  int w = tid >> 6, l = tid & 63;
  int lm = l & 15, q = l >> 4;
  int wm = w >> 1, wn = w & 1;
  int r = l >> 3, c = l & 7;
  int csw = (c ^ r) << 3;

  const unsigned short* pA0 = hbuf + (size_t)(base_slot + w * 32 +  0 + r) * H_I + csw;
  const unsigned short* pA1 = hbuf + (size_t)(base_slot + w * 32 +  8 + r) * H_I + csw;
  const unsigned short* pA2 = hbuf + (size_t)(base_slot + w * 32 + 16 + r) * H_I + csw;
  const unsigned short* pA3 = hbuf + (size_t)(base_slot + w * 32 + 24 + r) * H_I + csw;
  const unsigned short* pB0 = B + (size_t)(nt * 128 + w * 32 +  0 + r) * H_I + csw;
  const unsigned short* pB1 = B + (size_t)(nt * 128 + w * 32 +  8 + r) * H_I + csw;
  const unsigned short* pB2 = B + (size_t)(nt * 128 + w * 32 + 16 + r) * H_I + csw;
  const unsigned short* pB3 = B + (size_t)(nt * 128 + w * 32 + 24 + r) * H_I + csw;

  f32x4 acc[4][4];
#pragma unroll
  for (int i = 0; i < 4; ++i)
#pragma unroll
    for (int j = 0; j < 4; ++j) acc[i][j] = (f32x4){0.f, 0.f, 0.f, 0.f};

  for (int kt = 0; kt < H_I; kt += 64) {
    GLDS16(pA0 + kt, &sA[w * 32 +  0][0]);
    GLDS16(pA1 + kt, &sA[w * 32 +  8][0]);
    GLDS16(pA2 + kt, &sA[w * 32 + 16][0]);
    GLDS16(pA3 + kt, &sA[w * 32 + 24][0]);
    GLDS16(pB0 + kt, &sB[w * 32 +  0][0]);
    GLDS16(pB1 + kt, &sB[w * 32 +  8][0]);
    GLDS16(pB2 + kt, &sB[w * 32 + 16][0]);
    GLDS16(pB3 + kt, &sB[w * 32 + 24][0]);
    __syncthreads();
    bf16x8 af[2][4], bfr[2][4];
#pragma unroll
    for (int s = 0; s < 2; ++s) {
#pragma unroll
      for (int i = 0; i < 4; ++i) {
        int row = wm * 64 + i * 16 + lm;
        af[s][i] = *(const bf16x8*)&sA[row][(((s << 2) + q) ^ (lm & 7)) << 3];
      }
#pragma unroll
      for (int j = 0; j < 4; ++j) {
        int row = wn * 64 + j * 16 + lm;
        bfr[s][j] = *(const bf16x8*)&sB[row][(((s << 2) + q) ^ (lm & 7)) << 3];
      }
    }
#pragma unroll
    for (int s = 0; s < 2; ++s)
#pragma unroll
      for (int i = 0; i < 4; ++i)
#pragma unroll
        for (int j = 0; j < 4; ++j)
          acc[i][j] = __builtin_amdgcn_mfma_f32_16x16x32_bf16(af[s][i], bfr[s][j], acc[i][j], 0, 0, 0);
    __syncthreads();
  }

  int colbase = nt * 128 + wn * 64;
#pragma unroll
  for (int i = 0; i < 4; ++i) {
#pragma unroll
    for (int rr = 0; rr < 4; ++rr) {
      int row = wm * 64 + i * 16 + q * 4 + rr;
      unsigned short* orow = Yout + (size_t)(base_slot + row) * D_IN + colbase + lm;
#pragma unroll
      for (int j = 0; j < 4; ++j)
        orow[j * 16] = f2bf(acc[i][j][rr]);
    }
  }
}

// ---------------- out[t] = sum_k Yout[slot_k(t)] + Yout[shared_slot(t)] ----------------
__global__ __launch_bounds__(256) void reduce_out(
    const unsigned short* __restrict__ Yout, const int* __restrict__ tok2slot,
    const int* __restrict__ cnt, float4* __restrict__ out)
{
  int idx = blockIdx.x * 256 + threadIdx.x;   // [0, T*512)
  int t = idx >> 9, c = (idx & 511) << 2;     // 4 cols per thread
  int sb = 0;
  for (int e = 0; e < NE; ++e) sb += (cnt[e] + 127) & ~127;
  int sl[5];
  sl[0] = sb + t;
#pragma unroll
  for (int k = 0; k < TOPK; ++k) sl[k + 1] = tok2slot[t * TOPK + k];
  float4 a = {0.f, 0.f, 0.f, 0.f};
#pragma unroll
  for (int k = 0; k < 5; ++k) {
    ushort4 v = *(const ushort4*)(Yout + (size_t)sl[k] * D_IN + c);
    a.x += bf2f(v.x); a.y += bf2f(v.y); a.z += bf2f(v.z); a.w += bf2f(v.w);
  }
  out[idx] = a;
}

extern "C" void kernel_launch(void* const* d_in, const int* in_sizes, int n_in,
                              void* d_out, int out_size, void* d_ws, size_t ws_size,
                              hipStream_t stream)
{
  const float* x   = (const float*)d_in[0];
  const float* gw  = (const float*)d_in[1];
  const float* w1  = (const float*)d_in[2];
  const float* w2  = (const float*)d_in[3];
  const float* sw1 = (const float*)d_in[4];
  const float* sw2 = (const float*)d_in[5];
  float* out = (float*)d_out;

  char* ws = (char*)d_ws;
  size_t off = 0;
  auto alloc = [&](size_t bytes) -> char* {
    char* p = ws + off; off += (bytes + 255) & ~(size_t)255; return p;
  };
  unsigned short* xbf   = (unsigned short*)alloc((size_t)T_TOK * D_IN * 2);
  unsigned short* w1bf  = (unsigned short*)alloc((size_t)NE * TWOH * D_IN * 2);   // 128 MB; reused as Yout
  unsigned short* w2bf  = (unsigned short*)alloc((size_t)NE * D_IN * H_I * 2);
  unsigned short* sw1bf = (unsigned short*)alloc((size_t)TWOH * D_IN * 2);
  unsigned short* sw2bf = (unsigned short*)alloc((size_t)D_IN * H_I * 2);
  unsigned short* hbuf  = (unsigned short*)alloc((size_t)MAX_SLOTS * H_I * 2);
  int*   cnt    = (int*)alloc(NE * 4);
  int*   captok = (int*)alloc((size_t)NE * T_TOK * 4);
  float* capw   = (float*)alloc((size_t)NE * T_TOK * 4);
  int*   stok   = (int*)alloc(MAX_SLOTS * 4);
  float* swt    = (float*)alloc(MAX_SLOTS * 4);
  int*   tk_ep  = (int*)alloc((size_t)T_TOK * TOPK * 4);
  int*   t2s    = (int*)alloc((size_t)T_TOK * TOPK * 4);
  int*   tmap   = (int*)alloc((MAX_TILES + 1) * 4);
  if (off > ws_size) return;  // ws too small: leave out poisoned as diagnostic

  // fc2 output (bf16) aliases w1bf (dead after fc1): 12288*2048*2 = 50.3 MB <= 128 MB
  unsigned short* Yout = (unsigned short*)w1bf;

  cvt_all<<<(R_SW2 + 255) / 256, 256, 0, stream>>>(
      (const float4*)x, (const float4*)w1, (const float4*)w2,
      (const float4*)sw1, (const float4*)sw2,
      (ushort4*)xbf, (ushort4*)w1bf, (ushort4*)w2bf, (ushort4*)sw1bf, (ushort4*)sw2bf, cnt);

  gate_topk<<<T_TOK, 256, 0, stream>>>(x, gw, cnt, captok, capw, tk_ep);
  compact_lists<<<(NE * T_TOK + T_TOK + TOPK * T_TOK) / 256, 256, 0, stream>>>(
      cnt, captok, capw, tk_ep, stok, swt, t2s, tmap);
  fc1_fused<<<MAX_TILES * 16, 256, 0, stream>>>(xbf, w1bf, sw1bf, stok, swt, tmap, hbuf);
  fc2_gemm<<<MAX_TILES * 16, 256, 0, stream>>>(hbuf, w2bf, sw2bf, tmap, Yout);
  reduce_out<<<(T_TOK * 512) / 256, 256, 0, stream>>>(Yout, t2s, cnt, (float4*)out);
}

// Round 7
// 785.834 us; speedup vs baseline: 1.1492x; 1.0110x over previous
//
#include <hip/hip_runtime.h>
#include <stdint.h>

#define T_TOK 2048
#define D_IN  2048
#define H_I   1024
#define NE    16
#define TOPK  4
#define TWOH  2048
#define MAX_SLOTS 12288   // 16 experts padded (<=10224) + 2048 shared
#define MAX_TILES 96      // MAX_SLOTS / 128

typedef __attribute__((ext_vector_type(8))) __bf16 bf16x8;
typedef __attribute__((ext_vector_type(4))) float  f32x4;

__device__ __forceinline__ unsigned short f2bf(float f) {
  unsigned u = __float_as_uint(f);
  u += 0x7FFF + ((u >> 16) & 1);          // round-to-nearest-even
  return (unsigned short)(u >> 16);
}
__device__ __forceinline__ float bf2f(unsigned short s) {
  return __uint_as_float(((unsigned)s) << 16);
}

// per-block group metadata from cnt[] (compact_lists / reduce_out only)
__device__ __forceinline__ void group_meta(const int* __restrict__ cnt, int g,
                                           int& base, int& pc, int& shared_base) {
  int o = 0; base = 0; pc = T_TOK;
  for (int e = 0; e < NE; ++e) {
    int pce = (cnt[e] + 127) & ~127;
    if (e == g) { base = o; pc = pce; }
    o += pce;
  }
  shared_base = o;
  if (g == 16) base = o;
}

// async 16B global->LDS (lds dest = wave-uniform base + lane*16)
#define GLDS16(gp, lp) __builtin_amdgcn_global_load_lds( \
    (__attribute__((address_space(1))) void*)(gp),       \
    (__attribute__((address_space(3))) void*)(lp), 16, 0, 0)

// ---------------- fp32 -> bf16 convert, all tensors in one kernel ----------------
// float4 ranges: x 1048576 | w1 16777216 | w2 8388608 | sw1 1048576 | sw2 524288
#define R_X   1048576
#define R_W1  (R_X + 16777216)     // 17825792
#define R_W2  (R_W1 + 8388608)     // 26214400
#define R_SW1 (R_W2 + 1048576)     // 27262976
#define R_SW2 (R_SW1 + 524288)     // 27787264
__global__ void cvt_all(const float4* __restrict__ x,  const float4* __restrict__ w1,
                        const float4* __restrict__ w2, const float4* __restrict__ sw1,
                        const float4* __restrict__ sw2,
                        ushort4* __restrict__ xd,  ushort4* __restrict__ w1d,
                        ushort4* __restrict__ w2d, ushort4* __restrict__ sw1d,
                        ushort4* __restrict__ sw2d, int* __restrict__ cnt) {
  int i = blockIdx.x * 256 + threadIdx.x;
  if (i < NE) cnt[i] = 0;          // zero expert counters (stream-ordered before gate_topk)
  const float4* s; ushort4* d; int j;
  if      (i < R_X)   { s = x;   d = xd;   j = i; }
  else if (i < R_W1)  { s = w1;  d = w1d;  j = i - R_X; }
  else if (i < R_W2)  { s = w2;  d = w2d;  j = i - R_W1; }
  else if (i < R_SW1) { s = sw1; d = sw1d; j = i - R_W2; }
  else if (i < R_SW2) { s = sw2; d = sw2d; j = i - R_SW1; }
  else return;
  float4 f = s[j];
  ushort4 u;
  u.x = f2bf(f.x); u.y = f2bf(f.y); u.z = f2bf(f.z); u.w = f2bf(f.w);
  d[j] = u;
}

// ---------------- gate: logits -> softmax -> top4 -> per-expert lists ----------------
__global__ __launch_bounds__(256) void gate_topk(
    const float* __restrict__ x, const float* __restrict__ gw,
    int* __restrict__ cnt, int* __restrict__ cap_tok, float* __restrict__ cap_w,
    int* __restrict__ tk_ep)
{
  int t = blockIdx.x;
  const float* xr = x + (size_t)t * D_IN;
  float acc[NE];
#pragma unroll
  for (int e = 0; e < NE; ++e) acc[e] = 0.f;
  for (int d = threadIdx.x; d < D_IN; d += 256) {
    float xv = xr[d];
#pragma unroll
    for (int e = 0; e < NE; ++e) acc[e] += xv * gw[e * D_IN + d];
  }
#pragma unroll
  for (int e = 0; e < NE; ++e) {
    float v = acc[e];
#pragma unroll
    for (int o = 32; o > 0; o >>= 1) v += __shfl_down(v, o, 64);
    acc[e] = v;
  }
  __shared__ float red[4][NE];
  int wv = threadIdx.x >> 6, ln = threadIdx.x & 63;
  if (ln == 0) {
#pragma unroll
    for (int e = 0; e < NE; ++e) red[wv][e] = acc[e];
  }
  __syncthreads();
  if (threadIdx.x == 0) {
    float lg[NE];
    float mx = -1e30f;
#pragma unroll
    for (int e = 0; e < NE; ++e) {
      lg[e] = red[0][e] + red[1][e] + red[2][e] + red[3][e];
      mx = fmaxf(mx, lg[e]);
    }
    float s = 0.f;
#pragma unroll
    for (int e = 0; e < NE; ++e) { lg[e] = __expf(lg[e] - mx); s += lg[e]; }
    float inv = 1.f / s;
    bool used[NE] = {};
    for (int k = 0; k < TOPK; ++k) {
      float best = -1.f; int bi = 0;
      for (int e = 0; e < NE; ++e)
        if (!used[e] && lg[e] > best) { best = lg[e]; bi = e; }
      used[bi] = true;
      int pos = atomicAdd(&cnt[bi], 1);
      cap_tok[bi * T_TOK + pos] = t;
      cap_w[bi * T_TOK + pos]   = best * inv;
      tk_ep[t * TOPK + k] = (bi << 16) | pos;   // compaction preserves pos
    }
  }
}

// threads: [0, NE*T) expert caps | [NE*T, NE*T+T) shared | [.., +4T) tok2slot
// idx==0 additionally builds the dense worker-tile map: tmap[k] = (g<<16)|base_slot,
// tmap[MAX_TILES] = ntiles.
__global__ void compact_lists(const int* __restrict__ cnt,
                              const int* __restrict__ cap_tok, const float* __restrict__ cap_w,
                              const int* __restrict__ tk_ep,
                              int* __restrict__ stok, float* __restrict__ swt,
                              int* __restrict__ tok2slot, int* __restrict__ tmap)
{
  int idx = blockIdx.x * 256 + threadIdx.x;
  if (idx == 0) {
    int k = 0, o = 0;
    for (int e = 0; e < NE; ++e) {
      int pce = (cnt[e] + 127) & ~127;
      for (int m = 0; m * 128 < pce && k < MAX_TILES; ++m)
        tmap[k++] = (e << 16) | (o + m * 128);
      o += pce;
    }
    for (int m = 0; m < 16 && k < MAX_TILES; ++m)
      tmap[k++] = (16 << 16) | (o + m * 128);
    tmap[MAX_TILES] = k;
  }
  if (idx < NE * T_TOK) {
    int e = idx >> 11, pos = idx & (T_TOK - 1);
    int base, pc, sb;
    group_meta(cnt, e, base, pc, sb);
    if (pos < pc) {
      int dst = base + pos;
      if (pos < cnt[e]) { stok[dst] = cap_tok[idx]; swt[dst] = cap_w[idx]; }
      else              { stok[dst] = 0;            swt[dst] = 0.f; }
    }
  } else if (idx < NE * T_TOK + T_TOK) {
    int t = idx - NE * T_TOK;
    int base, pc, sb;
    group_meta(cnt, 16, base, pc, sb);
    stok[base + t] = t; swt[base + t] = 1.f;
  } else {
    int j = idx - NE * T_TOK - T_TOK;          // j in [0, 4T)
    int ep = tk_ep[j];
    int e = ep >> 16;
    int base, pc, sb;
    group_meta(cnt, e, base, pc, sb);
    tok2slot[j] = base + (ep & 0xFFFF);
  }
}

// ---------------- fused fc1 + silu-gating (BK=64, coalesced staging + 2-phase dbuf) ----------------
// Staging (round-5 verified): lane (r=l>>3, c=l&7); each GLDS16 covers 8 rows x 128B
// K-slice (8 cache lines/instr). Source pre-swizzled by c^r; ds_read applies
// chunk ^ (lm&7). NEW: double-buffered LDS, STAGE(next) issued BEFORE COMPUTE(cur);
// single vmcnt(0)+s_barrier per K-step AFTER the MFMAs so the ~600cyc compute phase
// covers the global-load latency (T3 minimum-2-phase; drain no longer on the
// stage->compute critical path).
__global__ __launch_bounds__(256) void fc1_fused(
    const unsigned short* __restrict__ xbf,
    const unsigned short* __restrict__ w1bf,
    const unsigned short* __restrict__ sw1bf,
    const int* __restrict__ stok, const float* __restrict__ swt,
    const int* __restrict__ tmap,
    unsigned short* __restrict__ hbuf)
{
  int bx = blockIdx.x;
  int tile = bx >> 4, nt = bx & 15;
  if (tile >= tmap[MAX_TILES]) return;
  int tg = tmap[tile];
  int g = tg >> 16, base_slot = tg & 0xFFFF;
  const unsigned short* B = (g == 16) ? sw1bf : w1bf + (size_t)g * TWOH * D_IN;

  __shared__ __align__(16) unsigned char smem[65536];   // 2 x (sA 16KB + sB 16KB)
  auto sG = (float (*)[64])smem;                        // [128][64] 32 KB (epilogue alias)

  int tid = threadIdx.x;
  int w = tid >> 6, l = tid & 63;
  int lm = l & 15, q = l >> 4;
  int wm = w >> 1, wn = w & 1;
  int r = l >> 3, c = l & 7;
  int csw = (c ^ r) << 3;          // pre-swizzled element offset within the 64-wide K-step

  // A: 16 chunks of 8 rows; wave w owns chunks 4w..4w+3 (rows w*32 .. w*32+31)
  const unsigned short* pA0 = xbf + (size_t)stok[base_slot + w * 32 +  0 + r] * D_IN + csw;
  const unsigned short* pA1 = xbf + (size_t)stok[base_slot + w * 32 +  8 + r] * D_IN + csw;
  const unsigned short* pA2 = xbf + (size_t)stok[base_slot + w * 32 + 16 + r] * D_IN + csw;
  const unsigned short* pA3 = xbf + (size_t)stok[base_slot + w * 32 + 24 + r] * D_IN + csw;
  // B: chunks cb = 4w..4w+3 of 16; cb<8 -> y row nt*64+8cb+r, cb>=8 -> gate row H_I+nt*64+8(cb-8)+r
  int cb0 = w * 4;
  int br0 = (cb0 + 0 < 8) ? (nt * 64 + (cb0 + 0) * 8 + r) : (H_I + nt * 64 + (cb0 - 8) * 8 + r);
  int br1 = (cb0 + 1 < 8) ? (nt * 64 + (cb0 + 1) * 8 + r) : (H_I + nt * 64 + (cb0 - 7) * 8 + r);
  int br2 = (cb0 + 2 < 8) ? (nt * 64 + (cb0 + 2) * 8 + r) : (H_I + nt * 64 + (cb0 - 6) * 8 + r);
  int br3 = (cb0 + 3 < 8) ? (nt * 64 + (cb0 + 3) * 8 + r) : (H_I + nt * 64 + (cb0 - 5) * 8 + r);
  const unsigned short* pB0 = B + (size_t)br0 * D_IN + csw;
  const unsigned short* pB1 = B + (size_t)br1 * D_IN + csw;
  const unsigned short* pB2 = B + (size_t)br2 * D_IN + csw;
  const unsigned short* pB3 = B + (size_t)br3 * D_IN + csw;

  f32x4 acc[4][4];
#pragma unroll
  for (int i = 0; i < 4; ++i)
#pragma unroll
    for (int j = 0; j < 4; ++j) acc[i][j] = (f32x4){0.f, 0.f, 0.f, 0.f};

#define STAGE_FC1(BUF, KT) do {                                          \
    unsigned char* b_ = smem + ((BUF) << 15);                            \
    auto sA_ = (unsigned short (*)[64])b_;                               \
    auto sB_ = (unsigned short (*)[64])(b_ + 16384);                     \
    GLDS16(pA0 + (KT), &sA_[w * 32 +  0][0]);                            \
    GLDS16(pA1 + (KT), &sA_[w * 32 +  8][0]);                            \
    GLDS16(pA2 + (KT), &sA_[w * 32 + 16][0]);                            \
    GLDS16(pA3 + (KT), &sA_[w * 32 + 24][0]);                            \
    GLDS16(pB0 + (KT), &sB_[w * 32 +  0][0]);                            \
    GLDS16(pB1 + (KT), &sB_[w * 32 +  8][0]);                            \
    GLDS16(pB2 + (KT), &sB_[w * 32 + 16][0]);                            \
    GLDS16(pB3 + (KT), &sB_[w * 32 + 24][0]);                            \
  } while (0)

#define COMPUTE_FC1(BUF) do {                                            \
    unsigned char* b_ = smem + ((BUF) << 15);                            \
    auto sA_ = (unsigned short (*)[64])b_;                               \
    auto sB_ = (unsigned short (*)[64])(b_ + 16384);                     \
    bf16x8 af[2][4], bfr[2][4];                                          \
    _Pragma("unroll")                                                    \
    for (int s = 0; s < 2; ++s) {                                        \
      _Pragma("unroll")                                                  \
      for (int i = 0; i < 4; ++i) {                                      \
        int row = wm * 64 + i * 16 + lm;                                 \
        af[s][i] = *(const bf16x8*)&sA_[row][(((s << 2) + q) ^ (lm & 7)) << 3]; \
      }                                                                  \
      _Pragma("unroll")                                                  \
      for (int j = 0; j < 4; ++j) {                                      \
        int row = wn * 64 + j * 16 + lm;                                 \
        bfr[s][j] = *(const bf16x8*)&sB_[row][(((s << 2) + q) ^ (lm & 7)) << 3]; \
      }                                                                  \
    }                                                                    \
    _Pragma("unroll")                                                    \
    for (int s = 0; s < 2; ++s)                                          \
      _Pragma("unroll")                                                  \
      for (int i = 0; i < 4; ++i)                                        \
        _Pragma("unroll")                                                \
        for (int j = 0; j < 4; ++j)                                      \
          acc[i][j] = __builtin_amdgcn_mfma_f32_16x16x32_bf16(af[s][i], bfr[s][j], acc[i][j], 0, 0, 0); \
  } while (0)

  STAGE_FC1(0, 0);
  asm volatile("s_waitcnt vmcnt(0)" ::: "memory");
  __builtin_amdgcn_s_barrier();
  for (int kt = 0; kt < D_IN; kt += 64) {
    int cur = (kt >> 6) & 1;
    if (kt + 64 < D_IN) STAGE_FC1(cur ^ 1, kt + 64);   // issue next-tile loads first
    COMPUTE_FC1(cur);                                  // MFMA covers load latency
    asm volatile("s_waitcnt vmcnt(0)" ::: "memory");   // next buf staged
    __builtin_amdgcn_s_barrier();                      // all waves done reading cur
  }
#undef STAGE_FC1
#undef COMPUTE_FC1

  // epilogue: gate waves push silu(g) through LDS (alias over smem — safe after barrier)
  if (wn == 1) {
#pragma unroll
    for (int i = 0; i < 4; ++i)
#pragma unroll
      for (int rr = 0; rr < 4; ++rr) {
        int row = wm * 64 + i * 16 + q * 4 + rr;
        int sw = (row & 3) << 4;                 // XOR swizzle: <=2-way bank alias (free)
#pragma unroll
        for (int j = 0; j < 4; ++j) {
          float gv = acc[i][j][rr];
          sG[row][(j * 16 + lm) ^ sw] = gv / (1.f + __expf(-gv));
        }
      }
  }
  __syncthreads();
  if (wn == 0) {
#pragma unroll
    for (int i = 0; i < 4; ++i)
#pragma unroll
      for (int rr = 0; rr < 4; ++rr) {
        int row = wm * 64 + i * 16 + q * 4 + rr;
        int slot = base_slot + row;
        float wt = swt[slot];
        int sw = (row & 3) << 4;
        unsigned short* hrow = hbuf + (size_t)slot * H_I + nt * 64;
#pragma unroll
        for (int j = 0; j < 4; ++j) {
          int col = j * 16 + lm;
          hrow[col] = f2bf(acc[i][j][rr] * sG[row][col ^ sw] * wt);
        }
      }
  }
}

// ---------------- grouped GEMM fc2 (BK=64, coalesced staging + 2-phase dbuf) ----------------
// Yout[slot, 0:2048] = h[slot] @ W2_g^T, bf16 out. Same scheme as fc1.
__global__ __launch_bounds__(256) void fc2_gemm(
    const unsigned short* __restrict__ hbuf,
    const unsigned short* __restrict__ w2bf,
    const unsigned short* __restrict__ sw2bf,
    const int* __restrict__ tmap,
    unsigned short* __restrict__ Yout)
{
  int bx = blockIdx.x;
  int tile = bx >> 4, nt = bx & 15;
  if (tile >= tmap[MAX_TILES]) return;
  int tg = tmap[tile];
  int g = tg >> 16, base_slot = tg & 0xFFFF;
  const unsigned short* B = (g == 16) ? sw2bf : w2bf + (size_t)g * D_IN * H_I;

  __shared__ __align__(16) unsigned char smem[65536];   // 2 x (sA 16KB + sB 16KB)

  int tid = threadIdx.x;
  int w = tid >> 6, l = tid & 63;
  int lm = l & 15, q = l >> 4;
  int wm = w >> 1, wn = w & 1;
  int r = l >> 3, c = l & 7;
  int csw = (c ^ r) << 3;

  const unsigned short* pA0 = hbuf + (size_t)(base_slot + w * 32 +  0 + r) * H_I + csw;
  const unsigned short* pA1 = hbuf + (size_t)(base_slot + w * 32 +  8 + r) * H_I + csw;
  const unsigned short* pA2 = hbuf + (size_t)(base_slot + w * 32 + 16 + r) * H_I + csw;
  const unsigned short* pA3 = hbuf + (size_t)(base_slot + w * 32 + 24 + r) * H_I + csw;
  const unsigned short* pB0 = B + (size_t)(nt * 128 + w * 32 +  0 + r) * H_I + csw;
  const unsigned short* pB1 = B + (size_t)(nt * 128 + w * 32 +  8 + r) * H_I + csw;
  const unsigned short* pB2 = B + (size_t)(nt * 128 + w * 32 + 16 + r) * H_I + csw;
  const unsigned short* pB3 = B + (size_t)(nt * 128 + w * 32 + 24 + r) * H_I + csw;

  f32x4 acc[4][4];
#pragma unroll
  for (int i = 0; i < 4; ++i)
#pragma unroll
    for (int j = 0; j < 4; ++j) acc[i][j] = (f32x4){0.f, 0.f, 0.f, 0.f};

#define STAGE_FC2(BUF, KT) do {                                          \
    unsigned char* b_ = smem + ((BUF) << 15);                            \
    auto sA_ = (unsigned short (*)[64])b_;                               \
    auto sB_ = (unsigned short (*)[64])(b_ + 16384);                     \
    GLDS16(pA0 + (KT), &sA_[w * 32 +  0][0]);                            \
    GLDS16(pA1 + (KT), &sA_[w * 32 +  8][0]);                            \
    GLDS16(pA2 + (KT), &sA_[w * 32 + 16][0]);                            \
    GLDS16(pA3 + (KT), &sA_[w * 32 + 24][0]);                            \
    GLDS16(pB0 + (KT), &sB_[w * 32 +  0][0]);                            \
    GLDS16(pB1 + (KT), &sB_[w * 32 +  8][0]);                            \
    GLDS16(pB2 + (KT), &sB_[w * 32 + 16][0]);                            \
    GLDS16(pB3 + (KT), &sB_[w * 32 + 24][0]);                            \
  } while (0)

#define COMPUTE_FC2(BUF) do {                                            \
    unsigned char* b_ = smem + ((BUF) << 15);                            \
    auto sA_ = (unsigned short (*)[64])b_;                               \
    auto sB_ = (unsigned short (*)[64])(b_ + 16384);                     \
    bf16x8 af[2][4], bfr[2][4];                                          \
    _Pragma("unroll")                                                    \
    for (int s = 0; s < 2; ++s) {                                        \
      _Pragma("unroll")                                                  \
      for (int i = 0; i < 4; ++i) {                                      \
        int row = wm * 64 + i * 16 + lm;                                 \
        af[s][i] = *(const bf16x8*)&sA_[row][(((s << 2) + q) ^ (lm & 7)) << 3]; \
      }                                                                  \
      _Pragma("unroll")                                                  \
      for (int j = 0; j < 4; ++j) {                                      \
        int row = wn * 64 + j * 16 + lm;                                 \
        bfr[s][j] = *(const bf16x8*)&sB_[row][(((s << 2) + q) ^ (lm & 7)) << 3]; \
      }                                                                  \
    }                                                                    \
    _Pragma("unroll")                                                    \
    for (int s = 0; s < 2; ++s)                                          \
      _Pragma("unroll")                                                  \
      for (int i = 0; i < 4; ++i)                                        \
        _Pragma("unroll")                                                \
        for (int j = 0; j < 4; ++j)                                      \
          acc[i][j] = __builtin_amdgcn_mfma_f32_16x16x32_bf16(af[s][i], bfr[s][j], acc[i][j], 0, 0, 0); \
  } while (0)

  STAGE_FC2(0, 0);
  asm volatile("s_waitcnt vmcnt(0)" ::: "memory");
  __builtin_amdgcn_s_barrier();
  for (int kt = 0; kt < H_I; kt += 64) {
    int cur = (kt >> 6) & 1;
    if (kt + 64 < H_I) STAGE_FC2(cur ^ 1, kt + 64);
    COMPUTE_FC2(cur);
    asm volatile("s_waitcnt vmcnt(0)" ::: "memory");
    __builtin_amdgcn_s_barrier();
  }
#undef STAGE_FC2
#undef COMPUTE_FC2

  int colbase = nt * 128 + wn * 64;
#pragma unroll
  for (int i = 0; i < 4; ++i) {
#pragma unroll
    for (int rr = 0; rr < 4; ++rr) {
      int row = wm * 64 + i * 16 + q * 4 + rr;
      unsigned short* orow = Yout + (size_t)(base_slot + row) * D_IN + colbase + lm;
#pragma unroll
      for (int j = 0; j < 4; ++j)
        orow[j * 16] = f2bf(acc[i][j][rr]);
    }
  }
}

// ---------------- out[t] = sum_k Yout[slot_k(t)] + Yout[shared_slot(t)] ----------------
__global__ __launch_bounds__(256) void reduce_out(
    const unsigned short* __restrict__ Yout, const int* __restrict__ tok2slot,
    const int* __restrict__ cnt, float4* __restrict__ out)
{
  int idx = blockIdx.x * 256 + threadIdx.x;   // [0, T*512)
  int t = idx >> 9, c = (idx & 511) << 2;     // 4 cols per thread
  int sb = 0;
  for (int e = 0; e < NE; ++e) sb += (cnt[e] + 127) & ~127;
  int sl[5];
  sl[0] = sb + t;
#pragma unroll
  for (int k = 0; k < TOPK; ++k) sl[k + 1] = tok2slot[t * TOPK + k];
  float4 a = {0.f, 0.f, 0.f, 0.f};
#pragma unroll
  for (int k = 0; k < 5; ++k) {
    ushort4 v = *(const ushort4*)(Yout + (size_t)sl[k] * D_IN + c);
    a.x += bf2f(v.x); a.y += bf2f(v.y); a.z += bf2f(v.z); a.w += bf2f(v.w);
  }
  out[idx] = a;
}

extern "C" void kernel_launch(void* const* d_in, const int* in_sizes, int n_in,
                              void* d_out, int out_size, void* d_ws, size_t ws_size,
                              hipStream_t stream)
{
  const float* x   = (const float*)d_in[0];
  const float* gw  = (const float*)d_in[1];
  const float* w1  = (const float*)d_in[2];
  const float* w2  = (const float*)d_in[3];
  const float* sw1 = (const float*)d_in[4];
  const float* sw2 = (const float*)d_in[5];
  float* out = (float*)d_out;

  char* ws = (char*)d_ws;
  size_t off = 0;
  auto alloc = [&](size_t bytes) -> char* {
    char* p = ws + off; off += (bytes + 255) & ~(size_t)255; return p;
  };
  unsigned short* xbf   = (unsigned short*)alloc((size_t)T_TOK * D_IN * 2);
  unsigned short* w1bf  = (unsigned short*)alloc((size_t)NE * TWOH * D_IN * 2);   // 128 MB; reused as Yout
  unsigned short* w2bf  = (unsigned short*)alloc((size_t)NE * D_IN * H_I * 2);
  unsigned short* sw1bf = (unsigned short*)alloc((size_t)TWOH * D_IN * 2);
  unsigned short* sw2bf = (unsigned short*)alloc((size_t)D_IN * H_I * 2);
  unsigned short* hbuf  = (unsigned short*)alloc((size_t)MAX_SLOTS * H_I * 2);
  int*   cnt    = (int*)alloc(NE * 4);
  int*   captok = (int*)alloc((size_t)NE * T_TOK * 4);
  float* capw   = (float*)alloc((size_t)NE * T_TOK * 4);
  int*   stok   = (int*)alloc(MAX_SLOTS * 4);
  float* swt    = (float*)alloc(MAX_SLOTS * 4);
  int*   tk_ep  = (int*)alloc((size_t)T_TOK * TOPK * 4);
  int*   t2s    = (int*)alloc((size_t)T_TOK * TOPK * 4);
  int*   tmap   = (int*)alloc((MAX_TILES + 1) * 4);
  if (off > ws_size) return;  // ws too small: leave out poisoned as diagnostic

  // fc2 output (bf16) aliases w1bf (dead after fc1): 12288*2048*2 = 50.3 MB <= 128 MB
  unsigned short* Yout = (unsigned short*)w1bf;

  cvt_all<<<(R_SW2 + 255) / 256, 256, 0, stream>>>(
      (const float4*)x, (const float4*)w1, (const float4*)w2,
      (const float4*)sw1, (const float4*)sw2,
      (ushort4*)xbf, (ushort4*)w1bf, (ushort4*)w2bf, (ushort4*)sw1bf, (ushort4*)sw2bf, cnt);

  gate_topk<<<T_TOK, 256, 0, stream>>>(x, gw, cnt, captok, capw, tk_ep);
  compact_lists<<<(NE * T_TOK + T_TOK + TOPK * T_TOK) / 256, 256, 0, stream>>>(
      cnt, captok, capw, tk_ep, stok, swt, t2s, tmap);
  fc1_fused<<<MAX_TILES * 16, 256, 0, stream>>>(xbf, w1bf, sw1bf, stok, swt, tmap, hbuf);
  fc2_gemm<<<MAX_TILES * 16, 256, 0, stream>>>(hbuf, w2bf, sw2bf, tmap, Yout);
  reduce_out<<<(T_TOK * 512) / 256, 256, 0, stream>>>(Yout, t2s, cnt, (float4*)out);
}